// Round 2
// baseline (472.616 us; speedup 1.0000x reference)
//
#include <hip/hip_runtime.h>

typedef _Float16 f16x8 __attribute__((ext_vector_type(8)));
typedef _Float16 f16x4 __attribute__((ext_vector_type(4)));
typedef _Float16 f16x2 __attribute__((ext_vector_type(2)));
typedef float f32x4 __attribute__((ext_vector_type(4)));
typedef float f32x2 __attribute__((ext_vector_type(2)));

#define GLD_LDS16(gp, lp)                                                        \
  __builtin_amdgcn_global_load_lds(                                              \
      (const __attribute__((address_space(1))) void*)(gp),                       \
      (__attribute__((address_space(3))) void*)(lp), 16, 0, 0)

// ---- prep: blocks [0,4096) convert x->f16 + row-block sum S; blocks [4096,5120)
// ---- convert weights (Cw = A-B, Bw = B) to f16.
__global__ void prep_k(const float* __restrict__ x, const float* __restrict__ A,
                       const float* __restrict__ B, _Float16* __restrict__ xh,
                       _Float16* __restrict__ Sh, _Float16* __restrict__ Cw,
                       _Float16* __restrict__ Bw) {
  const int t = threadIdx.x;
  if (blockIdx.x < 4096) {
    const int b = blockIdx.x;
    const f32x2* xr = (const f32x2*)(x + (size_t)b * 4096);
    f16x2* xo = (f16x2*)xh + (size_t)b * 2048;
    float s0 = 0.f, s1 = 0.f;
#pragma unroll
    for (int i = 0; i < 8; ++i) {
      f32x2 v = xr[i * 256 + t];
      f16x2 h;
      h.x = (_Float16)v.x; h.y = (_Float16)v.y;
      xo[i * 256 + t] = h;
      s0 += v.x; s1 += v.y;
    }
    f16x2 sv;
    sv.x = (_Float16)s0; sv.y = (_Float16)s1;
    ((f16x2*)Sh)[(size_t)b * 256 + t] = sv;
  } else {
    const int gid = (blockIdx.x - 4096) * 256 + t;
    f32x4 a = ((const f32x4*)A)[gid];
    f32x4 b4 = ((const f32x4*)B)[gid];
    f16x4 c, bb;
    c.x = (_Float16)(a.x - b4.x); c.y = (_Float16)(a.y - b4.y);
    c.z = (_Float16)(a.z - b4.z); c.w = (_Float16)(a.w - b4.w);
    bb.x = (_Float16)b4.x; bb.y = (_Float16)b4.y;
    bb.z = (_Float16)b4.z; bb.w = (_Float16)b4.w;
    ((f16x4*)Cw)[gid] = c;
    ((f16x4*)Bw)[gid] = bb;
  }
}

// ---------------- GEMM: out = Am[M,512] @ W[2048,512]^T ----------------
// Tile 128 x (128*NT), BK=32, 4 waves in 2x2, each wave 64m x (64*NT)n.
// MODE 0 (NT=1): writes f16 tvec[M,2048] (t = S @ B^T), M=4096.
// MODE 1 (NT=2): out[b*16384 + g*4096 + i*512 + h] = acc + tvec[b*2048+col],
//                row m = b*8+i, col = g*512+h, M=32768.
// LDS [row][k], 16B chunks XOR-swizzled phys = logical ^ ((row>>1)&3):
// 2-way max bank aliasing (free per m136). Swizzle applied on the GLOBAL
// source side because global_load_lds writes base + lane*16 (wave-uniform base).
template <int MODE, int NT>
__global__ __launch_bounds__(256) void gemm_k(const _Float16* __restrict__ Am,
                                              const _Float16* __restrict__ W,
                                              const _Float16* __restrict__ tvec,
                                              float* __restrict__ outf,
                                              _Float16* __restrict__ outh) {
  constexpr int BN = 128 * NT;    // tile n-width
  constexpr int NTN = 2048 / BN;  // n-tile count
  __shared__ __align__(16) _Float16 lA[128 * 32];
  __shared__ __align__(16) _Float16 lB[BN * 32];

  const int tid = threadIdx.x;
  const int lane = tid & 63;
  const int wv = tid >> 6;
  const int tile_n = blockIdx.x % NTN;  // n fast => same-m blocks adjacent in time
  const int tile_m = blockIdx.x / NTN;

  // Staging: chunk c = i*256 + tid; row = c>>2; note lc is i-invariant because
  // i advances row by 64 (≡0 mod 8), so one base pointer + i*64*512 offsets.
  const int row0 = tid >> 2;
  const int lc0 = (tid & 3) ^ ((row0 >> 1) & 3);
  const _Float16* gA0 = Am + ((size_t)(tile_m * 128 + row0) * 512 + lc0 * 8);
  const _Float16* gB0 = W + ((size_t)(tile_n * BN + row0) * 512 + lc0 * 8);
  _Float16* lpA0 = &lA[(size_t)(wv * 64) * 8];
  _Float16* lpB0 = &lB[(size_t)(wv * 64) * 8];

  const int lm = lane & 15;
  const int q = lane >> 4;
  const int mw = (wv >> 1) * 64;
  const int nw = (wv & 1) * (64 * NT);

  int aoff[4], boff[4 * NT];
#pragma unroll
  for (int f = 0; f < 4; ++f) {
    int rA = mw + f * 16 + lm;
    aoff[f] = rA * 32 + (q ^ ((rA >> 1) & 3)) * 8;
  }
#pragma unroll
  for (int f = 0; f < 4 * NT; ++f) {
    int rB = nw + f * 16 + lm;
    boff[f] = rB * 32 + (q ^ ((rB >> 1) & 3)) * 8;
  }

  f32x4 acc[4][4 * NT];
#pragma unroll
  for (int im = 0; im < 4; ++im)
#pragma unroll
    for (int in = 0; in < 4 * NT; ++in) acc[im][in] = (f32x4){0.f, 0.f, 0.f, 0.f};

  for (int kt = 0; kt < 16; ++kt) {
    __syncthreads();  // prior ds_reads drained before overwrite
#pragma unroll
    for (int i = 0; i < 2; ++i)
      GLD_LDS16(gA0 + (size_t)i * (64 * 512) + kt * 32, lpA0 + i * 256 * 8);
#pragma unroll
    for (int i = 0; i < 2 * NT; ++i)
      GLD_LDS16(gB0 + (size_t)i * (64 * 512) + kt * 32, lpB0 + i * 256 * 8);
    __syncthreads();  // staged data visible
    f16x8 af[4], bf[4 * NT];
#pragma unroll
    for (int f = 0; f < 4; ++f) af[f] = *(const f16x8*)&lA[aoff[f]];
#pragma unroll
    for (int f = 0; f < 4 * NT; ++f) bf[f] = *(const f16x8*)&lB[boff[f]];
#pragma unroll
    for (int im = 0; im < 4; ++im)
#pragma unroll
      for (int in = 0; in < 4 * NT; ++in)
        acc[im][in] =
            __builtin_amdgcn_mfma_f32_16x16x32_f16(af[im], bf[in], acc[im][in], 0, 0, 0);
  }

  // Epilogue. C/D layout: col = lane&15, row = q*4 + reg (m89-verified).
  // mbase ≡ 0 mod 4, (mbase&7) ∈ {0,4} -> all 4 regs share one b.
#pragma unroll
  for (int im = 0; im < 4; ++im) {
    const int mbase = tile_m * 128 + mw + im * 16 + q * 4;
    if (MODE == 1) {
      const int b = mbase >> 3;
      float* ob = outf + (size_t)b * 16384 + (size_t)(mbase & 7) * 512;
      const _Float16* tb = tvec + (size_t)b * 2048;
#pragma unroll
      for (int in = 0; in < 4 * NT; ++in) {
        const int col = tile_n * BN + nw + in * 16 + lm;
        const float tv = (float)tb[col];
        float* op = ob + (size_t)(col >> 9) * 4096 + (col & 511);
        f32x4 v = acc[im][in];
#pragma unroll
        for (int r = 0; r < 4; ++r)
          __builtin_nontemporal_store(v[r] + tv, op + r * 512);
      }
    } else {
      _Float16* ob = outh + (size_t)mbase * 2048;
#pragma unroll
      for (int in = 0; in < 4 * NT; ++in) {
        const int col = tile_n * BN + nw + in * 16 + lm;
        f32x4 v = acc[im][in];
#pragma unroll
        for (int r = 0; r < 4; ++r) ob[(size_t)r * 2048 + col] = (_Float16)v[r];
      }
    }
  }
}

extern "C" void kernel_launch(void* const* d_in, const int* in_sizes, int n_in,
                              void* d_out, int out_size, void* d_ws, size_t ws_size,
                              hipStream_t stream) {
  const float* x = (const float*)d_in[0];  // [4096, 4096]
  const float* A = (const float*)d_in[1];  // [4, 512, 512]
  const float* B = (const float*)d_in[2];  // [4, 512, 512]
  float* out = (float*)d_out;              // [4096, 16384]
  char* ws = (char*)d_ws;

  // ws: xh f16[32768*512] @0 (32MB); Sh f16[4096*512] @32MB (4MB);
  // Cw f16[2048*512] @36MB (2MB); Bw f16[2048*512] @38MB (2MB);
  // tvh f16[4096*2048] @40MB (16MB). Total 56MB.
  _Float16* xh = (_Float16*)(ws);
  _Float16* Sh = (_Float16*)(ws + 33554432u);
  _Float16* Cw = (_Float16*)(ws + 37748736u);
  _Float16* Bw = (_Float16*)(ws + 39845888u);
  _Float16* tvh = (_Float16*)(ws + 41943040u);

  prep_k<<<5120, 256, 0, stream>>>(x, A, B, xh, Sh, Cw, Bw);
  // t[b, g*512+h] = S[b,:] @ B[g,h,:] : M=4096 -> 32 m-tiles x 16 n-tiles = 512 blocks
  gemm_k<0, 1><<<512, 256, 0, stream>>>(Sh, Bw, nullptr, nullptr, tvh);
  // out = x @ (A-B)^T + t : M=32768 -> 256 m-tiles x 8 n-tiles = 2048 blocks
  gemm_k<1, 2><<<2048, 256, 0, stream>>>(xh, Cw, tvh, out, nullptr);
}